// Round 15
// baseline (182.569 us; speedup 1.0000x reference)
//
#include <hip/hip_runtime.h>
#include <cstdint>
#include <cstddef>

#define NG 3
#define NB 32
#define NT 1024
#define ND 512
#define NU 512
#define PLANE (NG * NB * NT)                        // 98304: one nt partial plane

typedef __bf16 bf16x8 __attribute__((ext_vector_type(8)));
typedef float  f32x4  __attribute__((ext_vector_type(4)));

static __device__ __forceinline__ unsigned int f2bf(float f) {
    union { float f; unsigned int u; } v; v.f = f;
    return (v.u + 0x7FFFu + ((v.u >> 16) & 1u)) >> 16;   // RNE f32->bf16
}
static __device__ __forceinline__ float bf2f(unsigned short h) {
    union { float f; unsigned int u; } v; v.u = ((unsigned int)h) << 16;
    return v.f;
}
static __device__ __forceinline__ unsigned int cvt_pk_bf16(float lo, float hi) {
    unsigned int r;
    asm("v_cvt_pk_bf16_f32 %0, %1, %2" : "=v"(r) : "v"(lo), "v"(hi));
    return r;
}
static __device__ __forceinline__ bf16x8 ld_bf16x8(const char* base, int off) {
    return __builtin_bit_cast(bf16x8, *(const uint4*)(base + off));
}

#define AS1(p) ((const __attribute__((address_space(1))) void*)(p))
#define AS3(p) ((__attribute__((address_space(3))) void*)(p))

// ---------- kernel 1: qb[g,b,u] = sum_d query[g,b,d]*W1[g,d,u] + b1 + b2 ----------
__global__ __launch_bounds__(256) void prep_qb_kernel(
    const float* __restrict__ query, const float* __restrict__ W1,
    const float* __restrict__ b1, const float* __restrict__ b2,
    float* __restrict__ qb)
{
    __shared__ float qs[NB][ND];                    // 64 KiB
    const int g  = blockIdx.x >> 3;
    const int uc = blockIdx.x & 7;
    const int tid = threadIdx.x;

    const float4* qsrc = (const float4*)(query + (size_t)g * NB * ND);
    #pragma unroll
    for (int i = 0; i < 16; ++i)
        ((float4*)&qs[0][0])[tid + i * 256] = qsrc[tid + i * 256];
    __syncthreads();

    const int u  = uc * 64 + (tid & 63);
    const int b0 = tid >> 6;                        // 0..3
    float acc[8] = {};
    const float* w1col = W1 + (size_t)g * ND * NU + u;
    for (int d = 0; d < ND; ++d) {
        float w = w1col[(size_t)d * NU];            // coalesced over u
        #pragma unroll
        for (int j = 0; j < 8; ++j)
            acc[j] = fmaf(qs[b0 + 4 * j][d], w, acc[j]);  // LDS broadcast
    }
    const float bias = b1[g * NU + u] + b2[g * NU + u];
    #pragma unroll
    for (int j = 0; j < 8; ++j)
        qb[((size_t)g * NB + (b0 + 4 * j)) * NU + u] = acc[j] + bias;
}

// ---------- kernel 2: w2t = DMA-ready, conflict-free bf16 image of W2^T ----------
// 8 KiB chunk keyed by (g, nt=u>>7, ktile=d>>5). In-chunk (frag-contiguous):
// [ub=(u>>4)&7][kgrp=(d>>3)&3][u16=u&15][e=d&7]*2B. A wave's B-frag read is
// laneoff=(l>>4)*256+(l&15)*16 -> 1 KiB contiguous -> ZERO bank conflicts.
__global__ __launch_bounds__(256) void prep_w2t_kernel(
    const float* __restrict__ W2, char* __restrict__ w2t)
{
    __shared__ float tile[64][65];                  // +1 pad: conflict-free transpose
    const int g  = blockIdx.x >> 6;
    const int tb = blockIdx.x & 63;
    const int d0 = (tb >> 3) * 64;
    const int u0 = (tb & 7) * 64;
    const int tx = threadIdx.x & 63;
    const int ty = threadIdx.x >> 6;

    const float* src = W2 + (size_t)g * ND * NU;
    #pragma unroll
    for (int k = 0; k < 16; ++k) {
        int r = ty + 4 * k;
        tile[r][tx] = src[(size_t)(d0 + r) * NU + (u0 + tx)];   // tile[d_loc][u_loc]
    }
    __syncthreads();
    #pragma unroll
    for (int k = 0; k < 16; ++k) {
        int ul = ty + 4 * k;
        int u  = u0 + ul;
        int d  = d0 + tx;
        unsigned short h = (unsigned short)f2bf(tile[tx][ul]);  // = W2[d][u]
        int nt = u >> 7, ub = (u >> 4) & 7, u16 = u & 15;
        int ktile = d >> 5, kgrp = (d >> 3) & 3, e = d & 7;
        size_t off = ((size_t)(((g << 2) + nt) << 4 | ktile) << 13)
                   + (size_t)((ub << 10) + (kgrp << 8) + (u16 << 4) + (e << 1));
        *(unsigned short*)(w2t + off) = h;
    }
}

// ---------- kernel 3: score GEMM, m97 geometry: 128x128 tile, BK=32 ----------
// 256 thr / 4 waves; wave = 64x64 out via 4x4 16x16x32 frags (8 LDS reads ->
// 16 MFMA = 0.5 KB/MFMA, under the 128 B/cyc LDS port even at full MFMA rate).
// B DMA'd (global_load_lds) from conflict-free image; A reg-loaded -> cvt ->
// LDS. ONE barrier per K-tile; NO manual waits (compiler schedules).
// Epilogue: tanh + V-dot + u-reduce per wave, then CROSS-WN LDS reduction
// (the round-14 bug: wn=0/1 partials raced on the same address).
__global__ __launch_bounds__(256, 3) void score_kernel(
    const float* __restrict__ values, const char* __restrict__ w2t,
    const float* __restrict__ qbg, const float* __restrict__ Vvec,
    unsigned short* __restrict__ parts)
{
    __shared__ char Ab[2][8192];                    // A dbuf: [rb8][kgrp4][r16][16B]
    __shared__ char Bb[2][8192];                    // B dbuf: same shape over u
    __shared__ float qbs[128];
    __shared__ float Vs[128];
    __shared__ float spart[2][128];                 // [wn][t-row]: cross-wn reduce

    const int blk = blockIdx.x;
    const int g   = blk >> 10;                      // 1024 blocks per g
    const int rem = blk & 1023;
    const int b   = rem >> 5;
    const int sub = rem & 31;
    const int tt  = sub >> 2;                       // 8 t-tiles of 128 rows
    const int nt  = sub & 3;                        // 4 u-tiles of 128 cols
    const int tid  = threadIdx.x;
    const int lane = tid & 63;
    const int wave = tid >> 6;
    const int wm   = wave >> 1;                     // 2 m-waves
    const int wn   = wave & 1;                      // 2 n-waves
    const int l16  = lane & 15;
    const int kg   = lane >> 4;

    const char* bimg = w2t + ((size_t)((((g << 2) + nt) << 4)) << 13);

    // qb/V slices for this u-tile
    if (tid < 128) {
        const float* qsrc = qbg + (((size_t)(g * NB + b)) << 9) + (nt << 7) + tid;
        __builtin_amdgcn_global_load_lds(AS1(qsrc), AS3(&qbs[tid]), 4, 0, 0);
    } else {
        const float* vsrc = Vvec + (g << 9) + (nt << 7) + (tid - 128);
        __builtin_amdgcn_global_load_lds(AS1(vsrc), AS3(&Vs[tid - 128]), 4, 0, 0);
    }

    // ---- A mapping: thread owns row ar (of 128), k-half kh (16 floats/tile)
    const int ar = tid >> 1;
    const int kh = tid & 1;
    const float* aptr = values
        + ((size_t)((g * NB + b) * NT + (tt << 7) + ar)) * ND + (kh << 4);
    const int awoff = ((ar >> 4) << 10) + (kh << 9) + ((ar & 15) << 4);

    float4 a0, a1, a2, a3;                          // named regs (rule #20)
    #define LOADA(KT_) do {                                               \
        const float4* _p = (const float4*)(aptr + ((KT_) << 5));          \
        a0 = _p[0]; a1 = _p[1]; a2 = _p[2]; a3 = _p[3];                   \
    } while (0)
    #define WRITEA(BUF_) do {                                             \
        uint4 _w0, _w1;                                                   \
        _w0.x = cvt_pk_bf16(a0.x, a0.y); _w0.y = cvt_pk_bf16(a0.z, a0.w); \
        _w0.z = cvt_pk_bf16(a1.x, a1.y); _w0.w = cvt_pk_bf16(a1.z, a1.w); \
        _w1.x = cvt_pk_bf16(a2.x, a2.y); _w1.y = cvt_pk_bf16(a2.z, a2.w); \
        _w1.z = cvt_pk_bf16(a3.x, a3.y); _w1.w = cvt_pk_bf16(a3.z, a3.w); \
        *(uint4*)((BUF_) + awoff)       = _w0;                            \
        *(uint4*)((BUF_) + awoff + 256) = _w1;                            \
    } while (0)
    #define STAGEB(KT_, BUF_) do {                                        \
        const char* _s = bimg + ((size_t)(KT_) << 13) + (tid << 4);       \
        __builtin_amdgcn_global_load_lds(AS1(_s),        AS3((BUF_) + (tid << 4)),        16, 0, 0); \
        __builtin_amdgcn_global_load_lds(AS1(_s + 4096), AS3((BUF_) + (tid << 4) + 4096), 16, 0, 0); \
    } while (0)

    // ---- prologue: tile 0 ----
    STAGEB(0, Bb[0]);
    LOADA(0);
    WRITEA(Ab[0]);                                  // compiler inserts vmcnt for a0..a3
    __syncthreads();                                // drains B(0) DMA + A writes

    const int laneoff = (kg << 8) + (l16 << 4);     // frag addr: contiguous 1 KiB/wave
    const int abase = wm << 12;
    const int bbase = wn << 12;

    f32x4 acc[4][4];
    #pragma unroll
    for (int mf = 0; mf < 4; ++mf)
        #pragma unroll
        for (int nf = 0; nf < 4; ++nf)
            acc[mf][nf] = (f32x4)(0.0f);

    #pragma unroll 1
    for (int kt = 0; kt < 16; ++kt) {
        const char* Ac = Ab[kt & 1];
        const char* Bc = Bb[kt & 1];
        if (kt < 15) {
            STAGEB(kt + 1, Bb[(kt + 1) & 1]);
            LOADA(kt + 1);
        }

        bf16x8 af[4], bfr[4];
        #pragma unroll
        for (int mf = 0; mf < 4; ++mf) af[mf]  = ld_bf16x8(Ac, abase + (mf << 10) + laneoff);
        #pragma unroll
        for (int nf = 0; nf < 4; ++nf) bfr[nf] = ld_bf16x8(Bc, bbase + (nf << 10) + laneoff);
        #pragma unroll
        for (int mf = 0; mf < 4; ++mf)
            #pragma unroll
            for (int nf = 0; nf < 4; ++nf)
                acc[mf][nf] = __builtin_amdgcn_mfma_f32_16x16x32_bf16(
                                  af[mf], bfr[nf], acc[mf][nf], 0, 0, 0);

        if (kt < 15) WRITEA(Ab[(kt + 1) & 1]);      // other buffer: no race
        __syncthreads();                            // one barrier per K-tile
    }
    #undef LOADA
    #undef WRITEA
    #undef STAGEB

    // ---- epilogue: tanh + V-dot; per-wave reduce over its 64 u-cols; deposit
    //      into spart[wn]; then cross-wn combine (the round-14 fix) ----
    const float CL = 2.8853900817779268f;           // 2*log2(e)
    #pragma unroll
    for (int mf = 0; mf < 4; ++mf) {
        float p[4] = {0.f, 0.f, 0.f, 0.f};
        #pragma unroll
        for (int nf = 0; nf < 4; ++nf) {
            const float qv = qbs[(wn << 6) + (nf << 4) + l16];
            const float vv = Vs [(wn << 6) + (nf << 4) + l16];
            #pragma unroll
            for (int r = 0; r < 4; ++r) {
                float x  = acc[mf][nf][r] + qv;
                float e  = exp2f(CL * x);
                float th = 1.0f - 2.0f * __builtin_amdgcn_rcpf(e + 1.0f);
                p[r] = fmaf(th, vv, p[r]);
            }
        }
        #pragma unroll
        for (int r = 0; r < 4; ++r) {
            float v = p[r];
            v += __shfl_xor(v, 1);
            v += __shfl_xor(v, 2);
            v += __shfl_xor(v, 4);
            v += __shfl_xor(v, 8);
            p[r] = v;
        }
        if (l16 == 0) {
            #pragma unroll
            for (int r = 0; r < 4; ++r)
                spart[wn][(wm << 6) + (mf << 4) + (kg << 2) + r] = p[r];
        }
    }
    __syncthreads();
    if (tid < 128) {
        float s = spart[0][tid] + spart[1][tid];
        unsigned short* prow = parts + (size_t)nt * PLANE
                             + ((size_t)(g * NB + b)) * NT + (tt << 7);
        prow[tid] = (unsigned short)f2bf(s);
    }
}

// ---------- kernel 4: softmax over T + context, 4 d-slices per (g,b) ----------
__global__ __launch_bounds__(256) void finish_kernel(
    const unsigned short* __restrict__ parts, const float* __restrict__ bV,
    const float* __restrict__ values,
    float* __restrict__ out_ctx, float* __restrict__ out_w)
{
    __shared__ float sl[NT];
    __shared__ float red[16];
    __shared__ float cred[4][128];
    const int blk   = blockIdx.x;
    const int gb    = blk >> 2;                     // 0..95
    const int slice = blk & 3;                      // d-slice of 128
    const int tid = threadIdx.x;
    const int lane = tid & 63, wid = tid >> 6;
    const float bv = bV[gb >> 5];

    float s[4];
    #pragma unroll
    for (int j = 0; j < 4; ++j) {
        size_t idx = (size_t)gb * NT + tid + 256 * j;
        s[j] = bf2f(parts[idx]) + bf2f(parts[idx + PLANE])
             + bf2f(parts[idx + 2 * PLANE]) + bf2f(parts[idx + 3 * PLANE]) + bv;
    }

    float m = fmaxf(fmaxf(s[0], s[1]), fmaxf(s[2], s[3]));
    #pragma unroll
    for (int mask = 32; mask; mask >>= 1) m = fmaxf(m, __shfl_xor(m, mask));
    if (lane == 0) red[wid] = m;
    __syncthreads();
    const float gm = fmaxf(fmaxf(red[0], red[1]), fmaxf(red[2], red[3]));

    float e[4], ps = 0.f;
    #pragma unroll
    for (int j = 0; j < 4; ++j) { e[j] = __expf(s[j] - gm); ps += e[j]; }
    #pragma unroll
    for (int mask = 32; mask; mask >>= 1) ps += __shfl_xor(ps, mask);
    if (lane == 0) red[8 + wid] = ps;
    __syncthreads();
    const float inv = 1.f / (red[8] + red[9] + red[10] + red[11]);

    #pragma unroll
    for (int j = 0; j < 4; ++j) {
        float w = e[j] * inv;
        sl[tid + 256 * j] = w;
        if (slice == 0) out_w[(size_t)gb * NT + tid + 256 * j] = w;
    }
    __syncthreads();

    const int dp = tid & 63;
    const int tg = tid >> 6;
    const float* vbase = values + (size_t)gb * NT * ND + slice * 128 + dp * 2;
    float ax = 0.f, ay = 0.f;
    #pragma unroll 4
    for (int t = tg; t < NT; t += 4) {
        float2 v = *(const float2*)(vbase + (size_t)t * ND);
        float w = sl[t];
        ax = fmaf(w, v.x, ax);
        ay = fmaf(w, v.y, ay);
    }
    cred[tg][dp * 2]     = ax;
    cred[tg][dp * 2 + 1] = ay;
    __syncthreads();
    if (tid < 128) {
        float r = cred[0][tid] + cred[1][tid] + cred[2][tid] + cred[3][tid];
        out_ctx[(size_t)gb * ND + slice * 128 + tid] = r;
    }
}

extern "C" void kernel_launch(void* const* d_in, const int* in_sizes, int n_in,
                              void* d_out, int out_size, void* d_ws, size_t ws_size,
                              hipStream_t stream)
{
    (void)in_sizes; (void)n_in; (void)out_size; (void)ws_size;
    const float* query  = (const float*)d_in[0];
    const float* values = (const float*)d_in[1];
    const float* W1     = (const float*)d_in[2];
    const float* b1     = (const float*)d_in[3];
    const float* W2     = (const float*)d_in[4];
    const float* b2     = (const float*)d_in[5];
    const float* Vv     = (const float*)d_in[6];
    const float* bV     = (const float*)d_in[7];

    float* out_ctx = (float*)d_out;
    float* out_w   = out_ctx + (size_t)NG * NB * ND;

    // ws: qb fp32 192 KiB | parts bf16 4 planes 768 KiB | w2t image 1.5 MiB
    float* qb = (float*)d_ws;
    unsigned short* parts = (unsigned short*)(qb + (size_t)NG * NB * NU);
    char* w2t = (char*)(parts + (size_t)4 * PLANE);

    prep_qb_kernel <<<NG * 8,      256, 0, stream>>>(query, W1, b1, b2, qb);
    prep_w2t_kernel<<<NG * 64,     256, 0, stream>>>(W2, w2t);
    score_kernel   <<<NG * 1024,   256, 0, stream>>>(values, w2t, qb, Vv, parts);
    finish_kernel  <<<NG * NB * 4, 256, 0, stream>>>(parts, bV, values, out_ctx, out_w);
}